// Round 1
// baseline (901.387 us; speedup 1.0000x reference)
//
#include <hip/hip_runtime.h>
#include <math.h>

#define ACT_B 8
#define ACT_T 12
#define ACT_S 4096
#define ACT_D 512
#define ACT_THRESH 0.99f

// One wave (64 lanes) per (b,s) position. Each lane owns 8 floats of D=512
// (two float4s). Dot product via wave butterfly reduce -> halt decision is
// wave-uniform, so the early break is divergence-free.
__global__ __launch_bounds__(256) void act_scan_kernel(
    const float* __restrict__ h,
    const float* __restrict__ Wh,
    const float* __restrict__ bh,
    float* __restrict__ out,        // (B,S,D)
    float* __restrict__ eff_out,    // (B,S) assuming no never-halted position
    float* __restrict__ ws_cum,     // (B*S) final cum
    float* __restrict__ ws_nupfix,  // (B*S) n_up + running
    int* __restrict__ ws_flag)      // set if any position never halted
{
    const int wave = (blockIdx.x * blockDim.x + threadIdx.x) >> 6;
    const int lane = threadIdx.x & 63;
    const int b = wave >> 12;              // S = 4096
    const int s = wave & (ACT_S - 1);

    const int off0 = lane * 4;
    const int off1 = 256 + lane * 4;

    const float4 w0 = *(const float4*)(Wh + off0);
    const float4 w1 = *(const float4*)(Wh + off1);
    const float bias = bh[0];

    float4 a0 = make_float4(0.f, 0.f, 0.f, 0.f);
    float4 a1 = make_float4(0.f, 0.f, 0.f, 0.f);
    float cum = 0.f;
    int nup = 0;
    bool halted = false;

    const size_t planeStride = (size_t)ACT_S * ACT_D;   // stride between t planes
    const float* ht = h + (size_t)b * ACT_T * planeStride + (size_t)s * ACT_D;

    for (int t = 0; t < ACT_T; ++t) {
        const float4 h0 = *(const float4*)(ht + off0);
        const float4 h1 = *(const float4*)(ht + off1);
        float part = h0.x * w0.x + h0.y * w0.y + h0.z * w0.z + h0.w * w0.w
                   + h1.x * w1.x + h1.y * w1.y + h1.z * w1.z + h1.w * w1.w;
        #pragma unroll
        for (int m = 32; m > 0; m >>= 1)
            part += __shfl_xor(part, m, 64);
        // p = sigmoid(logit) * running; running == 1 until halt (we break at halt)
        const float p = 1.f / (1.f + expf(-(part + bias)));
        const float new_cum = cum + p;
        const bool halt = new_cum >= ACT_THRESH;
        const float rem = halt ? (1.f - cum) : p;
        a0.x += rem * h0.x; a0.y += rem * h0.y; a0.z += rem * h0.z; a0.w += rem * h0.w;
        a1.x += rem * h1.x; a1.y += rem * h1.y; a1.z += rem * h1.z; a1.w += rem * h1.w;
        nup += 1;
        cum = new_cum;
        if (halt) { halted = true; break; }
        ht += planeStride;
    }

    float* ob = out + (size_t)wave * ACT_D;   // wave == b*S + s
    *(float4*)(ob + off0) = a0;
    *(float4*)(ob + off1) = a1;

    if (lane == 0) {
        const float running = halted ? 0.f : 1.f;
        ws_cum[wave] = cum;
        ws_nupfix[wave] = (float)nup + running;
        // identity-branch effective_steps; overwritten by fixup if flag fires
        eff_out[wave] = (float)nup + fmaxf(1.f - cum, 0.f);
        if (!halted) atomicOr(ws_flag, 1);
    }
}

// Applies never_halted_branch to ALL positions iff any position never halted.
// Grid-uniform early exit in the (overwhelmingly likely) no-fixup case.
__global__ __launch_bounds__(256) void act_fixup_kernel(
    const float* __restrict__ h,
    float* __restrict__ out,
    float* __restrict__ eff_out,
    const float* __restrict__ ws_cum,
    const float* __restrict__ ws_nupfix,
    const int* __restrict__ ws_flag)
{
    if (*ws_flag == 0) return;
    const int wave = (blockIdx.x * blockDim.x + threadIdx.x) >> 6;
    const int lane = threadIdx.x & 63;
    const int b = wave >> 12;
    const int s = wave & (ACT_S - 1);
    const int off0 = lane * 4;
    const int off1 = 256 + lane * 4;

    const float cum = ws_cum[wave];
    const float c = 1.f - cum;

    const size_t planeStride = (size_t)ACT_S * ACT_D;
    const float* hl = h + ((size_t)b * ACT_T + (ACT_T - 1)) * planeStride
                        + (size_t)s * ACT_D;
    float* ob = out + (size_t)wave * ACT_D;

    const float4 h0 = *(const float4*)(hl + off0);
    const float4 h1 = *(const float4*)(hl + off1);
    float4 o0 = *(float4*)(ob + off0);
    float4 o1 = *(float4*)(ob + off1);
    o0.x += c * h0.x; o0.y += c * h0.y; o0.z += c * h0.z; o0.w += c * h0.w;
    o1.x += c * h1.x; o1.y += c * h1.y; o1.z += c * h1.z; o1.w += c * h1.w;
    *(float4*)(ob + off0) = o0;
    *(float4*)(ob + off1) = o1;

    if (lane == 0)
        eff_out[wave] = ws_nupfix[wave] + fmaxf(c, 0.f);
}

// ponder_cost[b] = mean over S of effective_steps[b,:]
__global__ __launch_bounds__(256) void act_ponder_kernel(
    const float* __restrict__ eff, float* __restrict__ ponder)
{
    const int b = blockIdx.x;
    float sum = 0.f;
    for (int s = threadIdx.x; s < ACT_S; s += 256)
        sum += eff[b * ACT_S + s];
    #pragma unroll
    for (int m = 32; m > 0; m >>= 1)
        sum += __shfl_xor(sum, m, 64);
    __shared__ float red[4];
    if ((threadIdx.x & 63) == 0) red[threadIdx.x >> 6] = sum;
    __syncthreads();
    if (threadIdx.x == 0)
        ponder[b] = (red[0] + red[1] + red[2] + red[3]) * (1.0f / ACT_S);
}

extern "C" void kernel_launch(void* const* d_in, const int* in_sizes, int n_in,
                              void* d_out, int out_size, void* d_ws, size_t ws_size,
                              hipStream_t stream)
{
    const float* h  = (const float*)d_in[0];   // (B,T,S,D) fp32
    const float* Wh = (const float*)d_in[1];   // (D,)
    const float* bh = (const float*)d_in[2];   // (1,)

    float* out    = (float*)d_out;                               // B*S*D
    float* ponder = out + (size_t)ACT_B * ACT_S * ACT_D;         // B
    float* eff    = ponder + ACT_B;                              // B*S

    float* ws_cum    = (float*)d_ws;
    float* ws_nupfix = ws_cum + ACT_B * ACT_S;
    int*   ws_flag   = (int*)(ws_nupfix + ACT_B * ACT_S);

    hipMemsetAsync(ws_flag, 0, sizeof(int), stream);

    const int waves = ACT_B * ACT_S;          // 32768 positions
    dim3 grid(waves / 4), block(256);         // 4 waves per block
    act_scan_kernel<<<grid, block, 0, stream>>>(h, Wh, bh, out, eff,
                                                ws_cum, ws_nupfix, ws_flag);
    act_fixup_kernel<<<grid, block, 0, stream>>>(h, out, eff,
                                                 ws_cum, ws_nupfix, ws_flag);
    act_ponder_kernel<<<ACT_B, 256, 0, stream>>>(eff, ponder);
}